// Round 8
// baseline (357.154 us; speedup 1.0000x reference)
//
#include <hip/hip_runtime.h>
#include <cfloat>

#define N_PTS 8192
#define DTOK 256
#define KNN 16
#define NCHUNK 16
#define CHUNK 512   // N_PTS / NCHUNK

typedef __attribute__((ext_vector_type(8))) short short8;
typedef __attribute__((ext_vector_type(4))) float float4v;

__device__ inline short f2bf(float f) {   // RTNE fp32 -> bf16
  unsigned u = __float_as_uint(f);
  u += 0x7fffu + ((u >> 16) & 1u);
  return (short)(u >> 16);
}
__device__ inline float bf2f(short h) {
  return __uint_as_float(((unsigned)(unsigned short)h) << 16);
}

// ---------------------------------------------------------------------------
// thresh[i] = FLT_MAX (ws is poisoned to 0xAA = negative floats every call).
// ---------------------------------------------------------------------------
__global__ __launch_bounds__(256) void thresh_init_kernel(float* t) {
  t[blockIdx.x * 256 + threadIdx.x] = FLT_MAX;
}

// ---------------------------------------------------------------------------
// KNN stage 1 v3: deferred-insertion FIFO + cross-chunk shared threshold.
// Chunks publish their running bd[15] via atomicMin (float bits as int:
// valid, all d >= 0); other chunks prune pushes with d <= tb. Non-strict
// vs the foreign bound keeps tie-boundary candidates -> merged result is
// bit-identical to the reference ranking. Stale tb (XCD L2 non-coherence)
// only loosens pruning -- correctness never depends on it. Candidate loop
// x2-unrolled, one __any FIFO-space check per pair (cap 16, check at >=15).
// ---------------------------------------------------------------------------
__global__ __launch_bounds__(256) void knn_partial_kernel(
    const float* __restrict__ xyz, uint2* __restrict__ part,
    float* __restrict__ thresh) {
  __shared__ float4 s4[CHUNK];        // x,y,z,sq : 8 KB
  __shared__ uint2 sbuf[KNN][256];    // FIFO [slot][tid] : 32 KB
  const int t = threadIdx.x;
  const int cbase = blockIdx.y * CHUNK;

  #pragma unroll
  for (int r = 0; r < CHUNK / 256; ++r) {
    int jj = t + 256 * r;
    int j = cbase + jj;
    float x = xyz[3 * j], y = xyz[3 * j + 1], z = xyz[3 * j + 2];
    float sq = __fadd_rn(__fadd_rn(__fmul_rn(x, x), __fmul_rn(y, y)),
                         __fmul_rn(z, z));
    s4[jj] = make_float4(x, y, z, sq);
  }
  __syncthreads();

  const int i = blockIdx.x * 256 + t;
  const float xi = xyz[3 * i], yi = xyz[3 * i + 1], zi = xyz[3 * i + 2];
  const float sqi = __fadd_rn(__fadd_rn(__fmul_rn(xi, xi), __fmul_rn(yi, yi)),
                              __fmul_rn(zi, zi));
  volatile const float* vth = thresh + i;   // volatile: defeat CSE hoisting

  float bd[KNN];
  int bx[KNN];
  #pragma unroll
  for (int s = 0; s < KNN; ++s) { bd[s] = FLT_MAX; bx[s] = 0; }
  int cnt = 0;
  float pub = FLT_MAX;                      // last value we published

  auto drain = [&]() {
    int tt = 0;
    while (__any(tt < cnt)) {
      float d = FLT_MAX;
      int j = 0;
      if (tt < cnt) {
        uint2 e = sbuf[tt][t];
        d = __uint_as_float(e.x);
        j = (int)e.y;
      }
      bool c[KNN];
      #pragma unroll
      for (int s = 0; s < KNN; ++s) c[s] = d < bd[s];
      #pragma unroll
      for (int s = KNN - 1; s >= 1; --s) {
        bd[s] = c[s - 1] ? bd[s - 1] : (c[s] ? d : bd[s]);
        bx[s] = c[s - 1] ? bx[s - 1] : (c[s] ? j : bx[s]);
      }
      bd[0] = c[0] ? d : bd[0];
      bx[0] = c[0] ? j : bx[0];
      ++tt;
    }
    cnt = 0;
    if (bd[KNN - 1] < pub) {                // publish tightened bound
      atomicMin((int*)(thresh + i), __float_as_int(bd[KNN - 1]));
      pub = bd[KNN - 1];
    }
  };

  float tb = FLT_MAX;
  for (int jj = 0; jj < CHUNK; jj += 2) {
    if ((jj & 15) == 0) tb = *vth;          // refresh foreign bound
    #pragma unroll
    for (int u = 0; u < 2; ++u) {
      float4 p = s4[jj + u];
      float dot = fmaf(zi, p.z, fmaf(yi, p.y, __fmul_rn(xi, p.x)));
      float d = __fadd_rn(__fsub_rn(sqi, __fmul_rn(2.0f, dot)), p.w);
      int j = cbase + jj + u;
      if (j == i) d = __fadd_rn(d, 1e10f);
      if (d < bd[KNN - 1] && d <= tb) {
        sbuf[cnt][t] = make_uint2(__float_as_uint(d), (unsigned)j);
        ++cnt;
      }
    }
    if (__any(cnt >= KNN - 1)) drain();
  }
  drain();

  #pragma unroll
  for (int s = 0; s < KNN; ++s) {
    int slot = blockIdx.y * KNN + s;
    part[(size_t)slot * N_PTS + i] =
        make_uint2(__float_as_uint(bd[s]), (unsigned)bx[s]);
  }
}

// ---------------------------------------------------------------------------
// KNN stage 2 (unchanged R5 16-lane tournament merge).
// ---------------------------------------------------------------------------
__global__ __launch_bounds__(256) void knn_merge_kernel(
    const uint2* __restrict__ part, int* __restrict__ nbr) {
  __shared__ uint2 sl[KNN * 256];     // [slot][tid] : 32 KB
  const int t = threadIdx.x;
  const int c = t & 15;               // chunk this lane owns
  const int i = blockIdx.x * 16 + (t >> 4);

  float hd;  int hj;
  {
    uint2 e0 = part[(size_t)(c * KNN) * N_PTS + i];
    hd = __uint_as_float(e0.x);
    hj = (int)e0.y;
    #pragma unroll
    for (int s = 1; s < KNN; ++s)
      sl[s * 256 + t] = part[(size_t)(c * KNN + s) * N_PTS + i];
  }

  int idx = 1;
  int outj = 0;
  #pragma unroll
  for (int r = 0; r < KNN; ++r) {
    float md = hd;  int mc = c;
    #pragma unroll
    for (int m = 1; m < 16; m <<= 1) {
      float od = __shfl_xor(md, m, 16);
      int oc = __shfl_xor(mc, m, 16);
      bool take = (od < md) || (od == md && oc < mc);
      md = take ? od : md;
      mc = take ? oc : mc;
    }
    int jw = __shfl(hj, mc, 16);
    if (c == r) outj = jw;
    if (c == mc) {
      if (idx < KNN) {
        uint2 e = sl[idx * 256 + t];
        hd = __uint_as_float(e.x);
        hj = (int)e.y;
      } else {
        hd = FLT_MAX;  hj = 0;
      }
      ++idx;
    }
  }
  nbr[i * KNN + c] = outj;
}

// ---------------------------------------------------------------------------
// Split-precision prep (unchanged).
// ---------------------------------------------------------------------------
__global__ __launch_bounds__(256) void convert_a_kernel(
    const float* __restrict__ src, short* __restrict__ hi,
    short* __restrict__ lo) {
  const int idx = (blockIdx.x * 256 + threadIdx.x) * 4;
  const float4 v = *(const float4*)(src + idx);
  short h0 = f2bf(v.x), h1 = f2bf(v.y), h2 = f2bf(v.z), h3 = f2bf(v.w);
  short l0 = f2bf(v.x - bf2f(h0)), l1 = f2bf(v.y - bf2f(h1));
  short l2 = f2bf(v.z - bf2f(h2)), l3 = f2bf(v.w - bf2f(h3));
  *(uint2*)(hi + idx) = make_uint2(
      ((unsigned)(unsigned short)h0) | (((unsigned)(unsigned short)h1) << 16),
      ((unsigned)(unsigned short)h2) | (((unsigned)(unsigned short)h3) << 16));
  *(uint2*)(lo + idx) = make_uint2(
      ((unsigned)(unsigned short)l0) | (((unsigned)(unsigned short)l1) << 16),
      ((unsigned)(unsigned short)l2) | (((unsigned)(unsigned short)l3) << 16));
}

__global__ __launch_bounds__(256) void convert_w_kernel(
    const float* __restrict__ W1, short* __restrict__ bhi,
    short* __restrict__ blo) {
  const int n = blockIdx.x;      // 0..511
  const int k = threadIdx.x;     // 0..255
  const float v = (n < 256) ? W1[k * DTOK + n]
                            : W1[(259 + k) * DTOK + (n - 256)];
  short h = f2bf(v);
  bhi[n * 256 + k] = h;
  blo[n * 256 + k] = f2bf(v - bf2f(h));
}

// ---------------------------------------------------------------------------
// pq GEMM (unchanged from R7; back-solved at ~7-10 us, not the bottleneck).
// ---------------------------------------------------------------------------
__global__ __launch_bounds__(256, 1) void pq_gemm_kernel(
    const short* __restrict__ Ahi, const short* __restrict__ Alo,
    const short* __restrict__ Bthi, const short* __restrict__ Btlo,
    const float* __restrict__ xyz, const float* __restrict__ W1,
    const float* __restrict__ b1, float* __restrict__ R,
    float* __restrict__ Q) {
  __shared__ char smem[33280];                 // K-loop: As+Bs (16KB) | epi: Qs
  __shared__ float sx[128][3];
  __shared__ float swz[6][64];
  __shared__ float sb1[64];
  short (*As)[32] = (short(*)[32])smem;        // 128 x 32 bf16
  short (*Bs)[32] = (short(*)[32])(smem + 8192);
  float (*Qs)[65] = (float(*)[65])smem;        // 128 x 65 fp32 (epilogue)

  const int tid = threadIdx.x;
  const int lane = tid & 63;
  const int wave = tid >> 6;
  const int l15 = lane & 15;
  const int quad = lane >> 4;
  const int mh = wave & 1;
  const int qh = wave >> 1;
  const int m0 = blockIdx.x * 128;
  const int np0 = blockIdx.y * 64;

  if (tid < 128) {
    sx[tid][0] = xyz[(m0 + tid) * 3];
    sx[tid][1] = xyz[(m0 + tid) * 3 + 1];
    sx[tid][2] = xyz[(m0 + tid) * 3 + 2];
  } else if (tid < 192) {
    int n = tid - 128;
    sb1[n] = b1[np0 + n];
    #pragma unroll
    for (int r = 0; r < 3; ++r) {
      swz[r][n] = W1[(256 + r) * DTOK + np0 + n];
      swz[3 + r][n] = W1[(515 + r) * DTOK + np0 + n];
    }
  }

  float4v acc[4][4];
  #pragma unroll
  for (int mf = 0; mf < 4; ++mf)
    #pragma unroll
    for (int nf = 0; nf < 4; ++nf)
      #pragma unroll
      for (int e = 0; e < 4; ++e) acc[mf][nf][e] = 0.f;

  const int sr = tid >> 2;
  const int sq = (tid & 3) * 8;

  #pragma unroll 1
  for (int pass = 0; pass < 3; ++pass) {
    const short* Asrc = (pass == 2) ? Alo : Ahi;
    const short* Bsrc = (pass == 1) ? Btlo : Bthi;
    #pragma unroll 1
    for (int kc = 0; kc < 8; ++kc) {
      const int k0 = kc * 32;
      __syncthreads();
      *(uint4*)(&As[sr][sq]) =
          *(const uint4*)(Asrc + (size_t)(m0 + sr) * 256 + k0 + sq);
      *(uint4*)(&As[sr + 64][sq]) =
          *(const uint4*)(Asrc + (size_t)(m0 + sr + 64) * 256 + k0 + sq);
      *(uint4*)(&Bs[sr][sq]) =
          *(const uint4*)(Bsrc + (size_t)(np0 + sr) * 256 + k0 + sq);
      *(uint4*)(&Bs[sr + 64][sq]) =
          *(const uint4*)(Bsrc + (size_t)(256 + np0 + sr) * 256 + k0 + sq);
      __syncthreads();

      short8 af[4], bf[4];
      #pragma unroll
      for (int mf = 0; mf < 4; ++mf)
        af[mf] = *(const short8*)(&As[mh * 64 + mf * 16 + l15][quad * 8]);
      #pragma unroll
      for (int nf = 0; nf < 4; ++nf)
        bf[nf] = *(const short8*)(&Bs[qh * 64 + nf * 16 + l15][quad * 8]);
      #pragma unroll
      for (int mf = 0; mf < 4; ++mf)
        #pragma unroll
        for (int nf = 0; nf < 4; ++nf)
          acc[mf][nf] = __builtin_amdgcn_mfma_f32_16x16x32_bf16(
              af[mf], bf[nf], acc[mf][nf], 0, 0, 0);
    }
  }

  __syncthreads();
  if (qh == 1) {
    #pragma unroll
    for (int mf = 0; mf < 4; ++mf)
      #pragma unroll
      for (int nf = 0; nf < 4; ++nf)
        #pragma unroll
        for (int e = 0; e < 4; ++e) {
          int row = mh * 64 + mf * 16 + quad * 4 + e;
          int col = nf * 16 + l15;
          float q = acc[mf][nf][e] + sx[row][0] * swz[3][col] +
                    sx[row][1] * swz[4][col] + sx[row][2] * swz[5][col];
          Qs[row][col] = q;
          Q[(size_t)(m0 + row) * DTOK + np0 + col] = q;
        }
  }
  __syncthreads();
  if (qh == 0) {
    #pragma unroll
    for (int mf = 0; mf < 4; ++mf)
      #pragma unroll
      for (int nf = 0; nf < 4; ++nf)
        #pragma unroll
        for (int e = 0; e < 4; ++e) {
          int row = mh * 64 + mf * 16 + quad * 4 + e;
          int col = nf * 16 + l15;
          float p = acc[mf][nf][e] + sx[row][0] * swz[0][col] +
                    sx[row][1] * swz[1][col] + sx[row][2] * swz[2][col];
          R[(size_t)(m0 + row) * DTOK + np0 + col] =
              (p + sb1[col]) - Qs[row][col];
        }
  }
}

// ---------------------------------------------------------------------------
// EdgeConv via MFMA. Build loop restructured: R_i loaded ONCE per point per
// wave (was re-loaded for each of the 16 k rows) -- cuts gather traffic
// 256 KB -> 136 KB per group. GEMM/epilogue unchanged.
// ---------------------------------------------------------------------------
#define EP 8          // points per group

__global__ __launch_bounds__(256, 2) void edge_mfma_kernel(
    const float* __restrict__ R, const float* __restrict__ Q,
    const int* __restrict__ nbr, const float* __restrict__ W2,
    const float* __restrict__ b2, float* __restrict__ out,
    int num_groups, int groups_per_block) {
  __shared__ short Hs[EP * KNN * DTOK];   // 128 rows x 256, 64 KB
  const int lane = threadIdx.x & 63;
  const int wave = threadIdx.x >> 6;
  const int l15 = lane & 15;
  const int quad = lane >> 4;

  short8 bfr[4][8];
  #pragma unroll
  for (int nt_i = 0; nt_i < 4; ++nt_i) {
    const int n = (wave * 4 + nt_i) * 16 + l15;
    #pragma unroll
    for (int kt = 0; kt < 8; ++kt) {
      short8 f;
      #pragma unroll
      for (int jj = 0; jj < 8; ++jj) {
        int k = kt * 32 + quad * 8 + jj;
        f[jj] = f2bf(W2[k * DTOK + n]);
      }
      bfr[nt_i][kt] = f;
    }
  }

  const int wc8 = lane >> 1;
  const int wsub = (lane & 1) * 4;

  for (int gi = 0; gi < groups_per_block; ++gi) {
    const int g = blockIdx.x + gi * gridDim.x;
    if (g >= num_groups) break;
    const int i0 = g * EP;

    // ---- build H: 2 points per wave, R_i hoisted out of the k loop ----
    #pragma unroll
    for (int pp = 0; pp < 2; ++pp) {
      const int i = i0 + wave * 2 + pp;
      const float4 ri = ((const float4*)(R + (size_t)i * DTOK))[lane];
      #pragma unroll 4
      for (int k = 0; k < KNN; ++k) {
        const int j = nbr[i * KNN + k];
        const float4 qj = ((const float4*)(Q + (size_t)j * DTOK))[lane];
        const int r = wave * 32 + pp * 16 + k;
        uint2 pk;
        pk.x = ((unsigned)(unsigned short)f2bf(fmaxf(ri.x + qj.x, 0.f))) |
               (((unsigned)(unsigned short)f2bf(fmaxf(ri.y + qj.y, 0.f))) << 16);
        pk.y = ((unsigned)(unsigned short)f2bf(fmaxf(ri.z + qj.z, 0.f))) |
               (((unsigned)(unsigned short)f2bf(fmaxf(ri.w + qj.w, 0.f))) << 16);
        *(uint2*)(&Hs[r * DTOK + ((wc8 ^ (r & 7)) << 3) + wsub]) = pk;
      }
    }
    __syncthreads();

    #pragma unroll
    for (int mp = 0; mp < 4; ++mp) {
      float4v acc[2][4];
      #pragma unroll
      for (int mi = 0; mi < 2; ++mi)
        #pragma unroll
        for (int nt_i = 0; nt_i < 4; ++nt_i)
          #pragma unroll
          for (int e = 0; e < 4; ++e) acc[mi][nt_i][e] = 0.f;

      #pragma unroll
      for (int kt = 0; kt < 8; ++kt) {
        const int pc = ((kt * 4 + quad) ^ (l15 & 7)) << 3;
        const short8 a0 = *(const short8*)(
            &Hs[((mp * 2 + 0) * 16 + l15) * DTOK + pc]);
        const short8 a1 = *(const short8*)(
            &Hs[((mp * 2 + 1) * 16 + l15) * DTOK + pc]);
        #pragma unroll
        for (int nt_i = 0; nt_i < 4; ++nt_i) {
          acc[0][nt_i] = __builtin_amdgcn_mfma_f32_16x16x32_bf16(
              a0, bfr[nt_i][kt], acc[0][nt_i], 0, 0, 0);
          acc[1][nt_i] = __builtin_amdgcn_mfma_f32_16x16x32_bf16(
              a1, bfr[nt_i][kt], acc[1][nt_i], 0, 0, 0);
        }
      }

      #pragma unroll
      for (int mi = 0; mi < 2; ++mi) {
        #pragma unroll
        for (int nt_i = 0; nt_i < 4; ++nt_i) {
          float rm = fmaxf(fmaxf(acc[mi][nt_i][0], acc[mi][nt_i][1]),
                           fmaxf(acc[mi][nt_i][2], acc[mi][nt_i][3]));
          rm = fmaxf(rm, __shfl_xor(rm, 16, 64));
          rm = fmaxf(rm, __shfl_xor(rm, 32, 64));
          if (lane < 16) {
            const int i = i0 + mp * 2 + mi;
            const int n = (wave * 4 + nt_i) * 16 + lane;
            out[(size_t)i * DTOK + n] = rm + b2[n];
          }
        }
      }
    }
    __syncthreads();
  }
}

// ---------------------------------------------------------------------------
extern "C" void kernel_launch(void* const* d_in, const int* in_sizes, int n_in,
                              void* d_out, int out_size, void* d_ws,
                              size_t ws_size, hipStream_t stream) {
  const float* xyz = (const float*)d_in[0];
  const float* feat = (const float*)d_in[1];
  const float* W1a = (const float*)d_in[2];
  const float* b1a = (const float*)d_in[3];
  const float* W2a = (const float*)d_in[4];
  const float* b2a = (const float*)d_in[5];
  const float* W1b = (const float*)d_in[6];
  const float* b1b = (const float*)d_in[7];
  const float* W2b = (const float*)d_in[8];
  const float* b2b = (const float*)d_in[9];
  float* out = (float*)d_out;

  // ws layout (25 MB): nbr 0.5 | 16MB (knn: part / gemm: Ahi,Alo,R)
  //                    | 8MB (knn: thresh / gemm: Q) | Bt hi/lo 0.5MB
  char* w = (char*)d_ws;
  const size_t SZ_NBR = (size_t)N_PTS * KNN * sizeof(int);        // 512 KB
  const size_t MB = 1024 * 1024;
  int* nbr = (int*)w;
  char* w1 = w + SZ_NBR;
  uint2* part = (uint2*)w1;                    // knn phase (16 MB)
  short* Ahi = (short*)w1;                     // 4 MB
  short* Alo = (short*)(w1 + 4 * MB);          // 4 MB
  float* R = (float*)(w1 + 8 * MB);            // 8 MB
  float* thresh = (float*)(w + SZ_NBR + 16 * MB);  // knn phase (32 KB)
  float* Q = (float*)(w + SZ_NBR + 16 * MB);   // 8 MB
  short* Bthi = (short*)(w + SZ_NBR + 24 * MB);// 256 KB
  short* Btlo = Bthi + 512 * 256;              // 256 KB
  float* bufC = out;                           // layer-a output staging

  thresh_init_kernel<<<N_PTS / 256, 256, 0, stream>>>(thresh);
  knn_partial_kernel<<<dim3(N_PTS / 256, NCHUNK), 256, 0, stream>>>(
      xyz, part, thresh);
  knn_merge_kernel<<<N_PTS / 16, 256, 0, stream>>>(part, nbr);

  const int num_groups = N_PTS / EP;           // 1024
  const int nblocks = 512;

  // layer a
  convert_w_kernel<<<512, 256, 0, stream>>>(W1a, Bthi, Btlo);
  convert_a_kernel<<<N_PTS * DTOK / 1024, 256, 0, stream>>>(feat, Ahi, Alo);
  pq_gemm_kernel<<<dim3(N_PTS / 128, 4), 256, 0, stream>>>(
      Ahi, Alo, Bthi, Btlo, xyz, W1a, b1a, R, Q);
  edge_mfma_kernel<<<nblocks, 256, 0, stream>>>(R, Q, nbr, W2a, b2a, bufC,
                                                num_groups, 2);

  // layer b
  convert_w_kernel<<<512, 256, 0, stream>>>(W1b, Bthi, Btlo);
  convert_a_kernel<<<N_PTS * DTOK / 1024, 256, 0, stream>>>(bufC, Ahi, Alo);
  pq_gemm_kernel<<<dim3(N_PTS / 128, 4), 256, 0, stream>>>(
      Ahi, Alo, Bthi, Btlo, xyz, W1b, b1b, R, Q);
  edge_mfma_kernel<<<nblocks, 256, 0, stream>>>(R, Q, nbr, W2b, b2b, out,
                                                num_groups, 2);
}

// Round 9
// 311.190 us; speedup vs baseline: 1.1477x; 1.1477x over previous
//
#include <hip/hip_runtime.h>
#include <cfloat>

#define N_PTS 8192
#define DTOK 256
#define KNN 16
#define NCHUNK 16
#define CHUNK 512   // N_PTS / NCHUNK

typedef __attribute__((ext_vector_type(8))) short short8;
typedef __attribute__((ext_vector_type(4))) float float4v;

__device__ inline short f2bf(float f) {   // RTNE fp32 -> bf16
  unsigned u = __float_as_uint(f);
  u += 0x7fffu + ((u >> 16) & 1u);
  return (short)(u >> 16);
}
__device__ inline float bf2f(short h) {
  return __uint_as_float(((unsigned)(unsigned short)h) << 16);
}

// ---------------------------------------------------------------------------
// KNN stage 1 (exact R5 version -- R8's shared-threshold variant regressed:
// atomic publishes + volatile reloads cost more than the drain savings).
// ---------------------------------------------------------------------------
__global__ __launch_bounds__(256) void knn_partial_kernel(
    const float* __restrict__ xyz, uint2* __restrict__ part) {
  __shared__ float4 s4[CHUNK];        // x,y,z,sq : 8 KB
  __shared__ uint2 sbuf[KNN][256];    // FIFO [slot][tid] : 32 KB
  const int t = threadIdx.x;
  const int cbase = blockIdx.y * CHUNK;

  #pragma unroll
  for (int r = 0; r < CHUNK / 256; ++r) {
    int jj = t + 256 * r;
    int j = cbase + jj;
    float x = xyz[3 * j], y = xyz[3 * j + 1], z = xyz[3 * j + 2];
    float sq = __fadd_rn(__fadd_rn(__fmul_rn(x, x), __fmul_rn(y, y)),
                         __fmul_rn(z, z));
    s4[jj] = make_float4(x, y, z, sq);
  }
  __syncthreads();

  const int i = blockIdx.x * 256 + t;
  const float xi = xyz[3 * i], yi = xyz[3 * i + 1], zi = xyz[3 * i + 2];
  const float sqi = __fadd_rn(__fadd_rn(__fmul_rn(xi, xi), __fmul_rn(yi, yi)),
                              __fmul_rn(zi, zi));

  float bd[KNN];
  int bx[KNN];
  #pragma unroll
  for (int s = 0; s < KNN; ++s) { bd[s] = FLT_MAX; bx[s] = 0; }
  int cnt = 0;

  auto drain = [&]() {
    int tt = 0;
    while (__any(tt < cnt)) {
      float d = FLT_MAX;
      int j = 0;
      if (tt < cnt) {
        uint2 e = sbuf[tt][t];
        d = __uint_as_float(e.x);
        j = (int)e.y;
      }
      bool c[KNN];
      #pragma unroll
      for (int s = 0; s < KNN; ++s) c[s] = d < bd[s];
      #pragma unroll
      for (int s = KNN - 1; s >= 1; --s) {
        bd[s] = c[s - 1] ? bd[s - 1] : (c[s] ? d : bd[s]);
        bx[s] = c[s - 1] ? bx[s - 1] : (c[s] ? j : bx[s]);
      }
      bd[0] = c[0] ? d : bd[0];
      bx[0] = c[0] ? j : bx[0];
      ++tt;
    }
    cnt = 0;
  };

  for (int jj = 0; jj < CHUNK; ++jj) {
    float4 p = s4[jj];
    float dot = fmaf(zi, p.z, fmaf(yi, p.y, __fmul_rn(xi, p.x)));
    float d = __fadd_rn(__fsub_rn(sqi, __fmul_rn(2.0f, dot)), p.w);
    int j = cbase + jj;
    if (j == i) d = __fadd_rn(d, 1e10f);
    if (d < bd[KNN - 1]) {
      sbuf[cnt][t] = make_uint2(__float_as_uint(d), (unsigned)j);
      ++cnt;
    }
    if (__any(cnt == KNN)) drain();
  }
  drain();

  #pragma unroll
  for (int s = 0; s < KNN; ++s) {
    int slot = blockIdx.y * KNN + s;
    part[(size_t)slot * N_PTS + i] =
        make_uint2(__float_as_uint(bd[s]), (unsigned)bx[s]);
  }
}

// ---------------------------------------------------------------------------
// KNN stage 2 (unchanged R5 16-lane tournament merge).
// ---------------------------------------------------------------------------
__global__ __launch_bounds__(256) void knn_merge_kernel(
    const uint2* __restrict__ part, int* __restrict__ nbr) {
  __shared__ uint2 sl[KNN * 256];     // [slot][tid] : 32 KB
  const int t = threadIdx.x;
  const int c = t & 15;               // chunk this lane owns
  const int i = blockIdx.x * 16 + (t >> 4);

  float hd;  int hj;
  {
    uint2 e0 = part[(size_t)(c * KNN) * N_PTS + i];
    hd = __uint_as_float(e0.x);
    hj = (int)e0.y;
    #pragma unroll
    for (int s = 1; s < KNN; ++s)
      sl[s * 256 + t] = part[(size_t)(c * KNN + s) * N_PTS + i];
  }

  int idx = 1;
  int outj = 0;
  #pragma unroll
  for (int r = 0; r < KNN; ++r) {
    float md = hd;  int mc = c;
    #pragma unroll
    for (int m = 1; m < 16; m <<= 1) {
      float od = __shfl_xor(md, m, 16);
      int oc = __shfl_xor(mc, m, 16);
      bool take = (od < md) || (od == md && oc < mc);
      md = take ? od : md;
      mc = take ? oc : mc;
    }
    int jw = __shfl(hj, mc, 16);
    if (c == r) outj = jw;
    if (c == mc) {
      if (idx < KNN) {
        uint2 e = sl[idx * 256 + t];
        hd = __uint_as_float(e.x);
        hj = (int)e.y;
      } else {
        hd = FLT_MAX;  hj = 0;
      }
      ++idx;
    }
  }
  nbr[i * KNN + c] = outj;
}

// ---------------------------------------------------------------------------
// W1 -> Bt (transposed, n-major) bf16 hi/lo (unchanged).
// ---------------------------------------------------------------------------
__global__ __launch_bounds__(256) void convert_w_kernel(
    const float* __restrict__ W1, short* __restrict__ bhi,
    short* __restrict__ blo) {
  const int n = blockIdx.x;      // 0..511
  const int k = threadIdx.x;     // 0..255
  const float v = (n < 256) ? W1[k * DTOK + n]
                            : W1[(259 + k) * DTOK + (n - 256)];
  short h = f2bf(v);
  bhi[n * 256 + k] = h;
  blo[n * 256 + k] = f2bf(v - bf2f(h));
}

// ---------------------------------------------------------------------------
// pq GEMM v2 (fused): A read as fp32, split to bf16 hi/lo in-register during
// staging (convert_a kernel deleted). K-loop: 8 chunks x 3 products
// (hi*hi + hi*lo + lo*hi) per chunk -- same MFMA count as R7's 3x24 but 3x
// fewer barriers. M-tile 64 -> grid 128x4 = 512 blocks = 2 blocks/CU (the
// R7 kernel ran 1 block/CU: zero overlap across its barrier drains).
// Wave w: mh=w&1 (rows mh*32..+31), qh=w>>1 (0: P strip, 1: Q strip).
// Epilogue: Q waves publish Q tile via LDS, P waves form R = P + b1 - Q.
// ---------------------------------------------------------------------------
__global__ __launch_bounds__(256, 2) void pq_gemm_fused_kernel(
    const float* __restrict__ A, const short* __restrict__ Bthi,
    const short* __restrict__ Btlo, const float* __restrict__ xyz,
    const float* __restrict__ W1, const float* __restrict__ b1,
    float* __restrict__ R, float* __restrict__ Q) {
  __shared__ short Ahi[64][32], Alo[64][32];    // 4K + 4K
  __shared__ short Bhi[128][32], Blo[128][32];  // 8K + 8K
  __shared__ float Qs[64][65];                  // 16.6K
  __shared__ float sx[64][3];
  __shared__ float swz[6][64];
  __shared__ float sb1[64];

  const int tid = threadIdx.x;
  const int lane = tid & 63;
  const int wave = tid >> 6;
  const int l15 = lane & 15;
  const int quad = lane >> 4;
  const int mh = wave & 1;
  const int qh = wave >> 1;
  const int m0 = blockIdx.x * 64;
  const int np0 = blockIdx.y * 64;

  if (tid < 64) {
    sx[tid][0] = xyz[(m0 + tid) * 3];
    sx[tid][1] = xyz[(m0 + tid) * 3 + 1];
    sx[tid][2] = xyz[(m0 + tid) * 3 + 2];
  } else if (tid < 128) {
    int n = tid - 64;
    sb1[n] = b1[np0 + n];
    #pragma unroll
    for (int r = 0; r < 3; ++r) {
      swz[r][n] = W1[(256 + r) * DTOK + np0 + n];
      swz[3 + r][n] = W1[(515 + r) * DTOK + np0 + n];
    }
  }

  float4v acc[2][4];
  #pragma unroll
  for (int mf = 0; mf < 2; ++mf)
    #pragma unroll
    for (int nf = 0; nf < 4; ++nf)
      #pragma unroll
      for (int e = 0; e < 4; ++e) acc[mf][nf][e] = 0.f;

  const int ar = tid >> 2;             // A staging row 0..63
  const int ak = (tid & 3) * 8;        // A staging k-offset

  #pragma unroll 1
  for (int kc = 0; kc < 8; ++kc) {
    const int k0 = kc * 32;
    __syncthreads();
    // ---- stage A (fp32 -> hi/lo bf16 in-register) ----
    {
      const float* asrc = A + (size_t)(m0 + ar) * 256 + k0 + ak;
      float4 a0 = *(const float4*)asrc;
      float4 a1 = *(const float4*)(asrc + 4);
      float v[8] = {a0.x, a0.y, a0.z, a0.w, a1.x, a1.y, a1.z, a1.w};
      short8 h8, l8;
      #pragma unroll
      for (int e = 0; e < 8; ++e) {
        short h = f2bf(v[e]);
        h8[e] = h;
        l8[e] = f2bf(v[e] - bf2f(h));
      }
      *(short8*)(&Ahi[ar][ak]) = h8;
      *(short8*)(&Alo[ar][ak]) = l8;
    }
    // ---- stage B (hi: l=0,1; lo: l=2,3) ----
    #pragma unroll
    for (int l = 0; l < 4; ++l) {
      const int rem = tid + 256 * (l & 1);
      const int row = rem >> 2;
      const int koff = (rem & 3) * 8;
      const int n = (row < 64) ? (np0 + row) : (256 + np0 + row - 64);
      const short* src = ((l < 2) ? Bthi : Btlo) + (size_t)n * 256 + k0 + koff;
      short8 vv = *(const short8*)src;
      if (l < 2) *(short8*)(&Bhi[row][koff]) = vv;
      else       *(short8*)(&Blo[row][koff]) = vv;
    }
    __syncthreads();

    // ---- fragments + 3-product MFMA ----
    short8 ah[2], al[2], bh[4], bl[4];
    #pragma unroll
    for (int mf = 0; mf < 2; ++mf) {
      ah[mf] = *(const short8*)(&Ahi[mh * 32 + mf * 16 + l15][quad * 8]);
      al[mf] = *(const short8*)(&Alo[mh * 32 + mf * 16 + l15][quad * 8]);
    }
    #pragma unroll
    for (int nf = 0; nf < 4; ++nf) {
      bh[nf] = *(const short8*)(&Bhi[qh * 64 + nf * 16 + l15][quad * 8]);
      bl[nf] = *(const short8*)(&Blo[qh * 64 + nf * 16 + l15][quad * 8]);
    }
    #pragma unroll
    for (int mf = 0; mf < 2; ++mf)
      #pragma unroll
      for (int nf = 0; nf < 4; ++nf) {
        acc[mf][nf] = __builtin_amdgcn_mfma_f32_16x16x32_bf16(
            ah[mf], bh[nf], acc[mf][nf], 0, 0, 0);
        acc[mf][nf] = __builtin_amdgcn_mfma_f32_16x16x32_bf16(
            ah[mf], bl[nf], acc[mf][nf], 0, 0, 0);
        acc[mf][nf] = __builtin_amdgcn_mfma_f32_16x16x32_bf16(
            al[mf], bh[nf], acc[mf][nf], 0, 0, 0);
      }
  }

  // ---- epilogue ----
  if (qh == 1) {                               // Q waves
    #pragma unroll
    for (int mf = 0; mf < 2; ++mf)
      #pragma unroll
      for (int nf = 0; nf < 4; ++nf)
        #pragma unroll
        for (int e = 0; e < 4; ++e) {
          int row = mh * 32 + mf * 16 + quad * 4 + e;
          int col = nf * 16 + l15;
          float q = acc[mf][nf][e] + sx[row][0] * swz[3][col] +
                    sx[row][1] * swz[4][col] + sx[row][2] * swz[5][col];
          Qs[row][col] = q;
          Q[(size_t)(m0 + row) * DTOK + np0 + col] = q;
        }
  }
  __syncthreads();
  if (qh == 0) {                               // P waves
    #pragma unroll
    for (int mf = 0; mf < 2; ++mf)
      #pragma unroll
      for (int nf = 0; nf < 4; ++nf)
        #pragma unroll
        for (int e = 0; e < 4; ++e) {
          int row = mh * 32 + mf * 16 + quad * 4 + e;
          int col = nf * 16 + l15;
          float p = acc[mf][nf][e] + sx[row][0] * swz[0][col] +
                    sx[row][1] * swz[1][col] + sx[row][2] * swz[2][col];
          R[(size_t)(m0 + row) * DTOK + np0 + col] =
              (p + sb1[col]) - Qs[row][col];
        }
  }
}

// ---------------------------------------------------------------------------
// EdgeConv via MFMA (unchanged from R8: R_i hoisted out of the k loop).
// ---------------------------------------------------------------------------
#define EP 8          // points per group

__global__ __launch_bounds__(256, 2) void edge_mfma_kernel(
    const float* __restrict__ R, const float* __restrict__ Q,
    const int* __restrict__ nbr, const float* __restrict__ W2,
    const float* __restrict__ b2, float* __restrict__ out,
    int num_groups, int groups_per_block) {
  __shared__ short Hs[EP * KNN * DTOK];   // 128 rows x 256, 64 KB
  const int lane = threadIdx.x & 63;
  const int wave = threadIdx.x >> 6;
  const int l15 = lane & 15;
  const int quad = lane >> 4;

  short8 bfr[4][8];
  #pragma unroll
  for (int nt_i = 0; nt_i < 4; ++nt_i) {
    const int n = (wave * 4 + nt_i) * 16 + l15;
    #pragma unroll
    for (int kt = 0; kt < 8; ++kt) {
      short8 f;
      #pragma unroll
      for (int jj = 0; jj < 8; ++jj) {
        int k = kt * 32 + quad * 8 + jj;
        f[jj] = f2bf(W2[k * DTOK + n]);
      }
      bfr[nt_i][kt] = f;
    }
  }

  const int wc8 = lane >> 1;
  const int wsub = (lane & 1) * 4;

  for (int gi = 0; gi < groups_per_block; ++gi) {
    const int g = blockIdx.x + gi * gridDim.x;
    if (g >= num_groups) break;
    const int i0 = g * EP;

    #pragma unroll
    for (int pp = 0; pp < 2; ++pp) {
      const int i = i0 + wave * 2 + pp;
      const float4 ri = ((const float4*)(R + (size_t)i * DTOK))[lane];
      #pragma unroll 4
      for (int k = 0; k < KNN; ++k) {
        const int j = nbr[i * KNN + k];
        const float4 qj = ((const float4*)(Q + (size_t)j * DTOK))[lane];
        const int r = wave * 32 + pp * 16 + k;
        uint2 pk;
        pk.x = ((unsigned)(unsigned short)f2bf(fmaxf(ri.x + qj.x, 0.f))) |
               (((unsigned)(unsigned short)f2bf(fmaxf(ri.y + qj.y, 0.f))) << 16);
        pk.y = ((unsigned)(unsigned short)f2bf(fmaxf(ri.z + qj.z, 0.f))) |
               (((unsigned)(unsigned short)f2bf(fmaxf(ri.w + qj.w, 0.f))) << 16);
        *(uint2*)(&Hs[r * DTOK + ((wc8 ^ (r & 7)) << 3) + wsub]) = pk;
      }
    }
    __syncthreads();

    #pragma unroll
    for (int mp = 0; mp < 4; ++mp) {
      float4v acc[2][4];
      #pragma unroll
      for (int mi = 0; mi < 2; ++mi)
        #pragma unroll
        for (int nt_i = 0; nt_i < 4; ++nt_i)
          #pragma unroll
          for (int e = 0; e < 4; ++e) acc[mi][nt_i][e] = 0.f;

      #pragma unroll
      for (int kt = 0; kt < 8; ++kt) {
        const int pc = ((kt * 4 + quad) ^ (l15 & 7)) << 3;
        const short8 a0 = *(const short8*)(
            &Hs[((mp * 2 + 0) * 16 + l15) * DTOK + pc]);
        const short8 a1 = *(const short8*)(
            &Hs[((mp * 2 + 1) * 16 + l15) * DTOK + pc]);
        #pragma unroll
        for (int nt_i = 0; nt_i < 4; ++nt_i) {
          acc[0][nt_i] = __builtin_amdgcn_mfma_f32_16x16x32_bf16(
              a0, bfr[nt_i][kt], acc[0][nt_i], 0, 0, 0);
          acc[1][nt_i] = __builtin_amdgcn_mfma_f32_16x16x32_bf16(
              a1, bfr[nt_i][kt], acc[1][nt_i], 0, 0, 0);
        }
      }

      #pragma unroll
      for (int mi = 0; mi < 2; ++mi) {
        #pragma unroll
        for (int nt_i = 0; nt_i < 4; ++nt_i) {
          float rm = fmaxf(fmaxf(acc[mi][nt_i][0], acc[mi][nt_i][1]),
                           fmaxf(acc[mi][nt_i][2], acc[mi][nt_i][3]));
          rm = fmaxf(rm, __shfl_xor(rm, 16, 64));
          rm = fmaxf(rm, __shfl_xor(rm, 32, 64));
          if (lane < 16) {
            const int i = i0 + mp * 2 + mi;
            const int n = (wave * 4 + nt_i) * 16 + lane;
            out[(size_t)i * DTOK + n] = rm + b2[n];
          }
        }
      }
    }
    __syncthreads();
  }
}

// ---------------------------------------------------------------------------
extern "C" void kernel_launch(void* const* d_in, const int* in_sizes, int n_in,
                              void* d_out, int out_size, void* d_ws,
                              size_t ws_size, hipStream_t stream) {
  const float* xyz = (const float*)d_in[0];
  const float* feat = (const float*)d_in[1];
  const float* W1a = (const float*)d_in[2];
  const float* b1a = (const float*)d_in[3];
  const float* W2a = (const float*)d_in[4];
  const float* b2a = (const float*)d_in[5];
  const float* W1b = (const float*)d_in[6];
  const float* b1b = (const float*)d_in[7];
  const float* W2b = (const float*)d_in[8];
  const float* b2b = (const float*)d_in[9];
  float* out = (float*)d_out;

  // ws layout (25 MB): nbr 0.5 | 16MB (knn: part / gemm: R at +8MB)
  //                    | Q 8MB | Bt hi/lo 0.5MB.  Layer-a staging in d_out.
  char* w = (char*)d_ws;
  const size_t SZ_NBR = (size_t)N_PTS * KNN * sizeof(int);        // 512 KB
  const size_t MB = 1024 * 1024;
  int* nbr = (int*)w;
  char* w1 = w + SZ_NBR;
  uint2* part = (uint2*)w1;                    // knn phase (16 MB)
  float* R = (float*)(w1 + 8 * MB);            // 8 MB (post-knn)
  float* Q = (float*)(w + SZ_NBR + 16 * MB);   // 8 MB
  short* Bthi = (short*)(w + SZ_NBR + 24 * MB);// 256 KB
  short* Btlo = Bthi + 512 * 256;              // 256 KB
  float* bufC = out;                           // layer-a output staging

  knn_partial_kernel<<<dim3(N_PTS / 256, NCHUNK), 256, 0, stream>>>(xyz, part);
  knn_merge_kernel<<<N_PTS / 16, 256, 0, stream>>>(part, nbr);

  const int num_groups = N_PTS / EP;           // 1024
  const int nblocks = 512;

  // layer a
  convert_w_kernel<<<512, 256, 0, stream>>>(W1a, Bthi, Btlo);
  pq_gemm_fused_kernel<<<dim3(N_PTS / 64, 4), 256, 0, stream>>>(
      feat, Bthi, Btlo, xyz, W1a, b1a, R, Q);
  edge_mfma_kernel<<<nblocks, 256, 0, stream>>>(R, Q, nbr, W2a, b2a, bufC,
                                                num_groups, 2);

  // layer b
  convert_w_kernel<<<512, 256, 0, stream>>>(W1b, Bthi, Btlo);
  pq_gemm_fused_kernel<<<dim3(N_PTS / 64, 4), 256, 0, stream>>>(
      bufC, Bthi, Btlo, xyz, W1b, b1b, R, Q);
  edge_mfma_kernel<<<nblocks, 256, 0, stream>>>(R, Q, nbr, W2b, b2b, out,
                                                num_groups, 2);
}

// Round 10
// 297.366 us; speedup vs baseline: 1.2011x; 1.0465x over previous
//
#include <hip/hip_runtime.h>
#include <cfloat>

#define N_PTS 8192
#define DTOK 256
#define KNN 16
#define NCHUNK 16
#define CHUNK 512   // N_PTS / NCHUNK

typedef __attribute__((ext_vector_type(8))) short short8;
typedef __attribute__((ext_vector_type(4))) float float4v;

__device__ inline short f2bf(float f) {   // RTNE fp32 -> bf16
  unsigned u = __float_as_uint(f);
  u += 0x7fffu + ((u >> 16) & 1u);
  return (short)(u >> 16);
}
__device__ inline float bf2f(short h) {
  return __uint_as_float(((unsigned)(unsigned short)h) << 16);
}

// ---------------------------------------------------------------------------
// KNN stage 1 (R5 + x2-unrolled candidate loop: one __any vote per pair;
// FIFO cap 16, check at >=15 -- semantics unchanged).
// ---------------------------------------------------------------------------
__global__ __launch_bounds__(256) void knn_partial_kernel(
    const float* __restrict__ xyz, uint2* __restrict__ part) {
  __shared__ float4 s4[CHUNK];        // x,y,z,sq : 8 KB
  __shared__ uint2 sbuf[KNN][256];    // FIFO [slot][tid] : 32 KB
  const int t = threadIdx.x;
  const int cbase = blockIdx.y * CHUNK;

  #pragma unroll
  for (int r = 0; r < CHUNK / 256; ++r) {
    int jj = t + 256 * r;
    int j = cbase + jj;
    float x = xyz[3 * j], y = xyz[3 * j + 1], z = xyz[3 * j + 2];
    float sq = __fadd_rn(__fadd_rn(__fmul_rn(x, x), __fmul_rn(y, y)),
                         __fmul_rn(z, z));
    s4[jj] = make_float4(x, y, z, sq);
  }
  __syncthreads();

  const int i = blockIdx.x * 256 + t;
  const float xi = xyz[3 * i], yi = xyz[3 * i + 1], zi = xyz[3 * i + 2];
  const float sqi = __fadd_rn(__fadd_rn(__fmul_rn(xi, xi), __fmul_rn(yi, yi)),
                              __fmul_rn(zi, zi));

  float bd[KNN];
  int bx[KNN];
  #pragma unroll
  for (int s = 0; s < KNN; ++s) { bd[s] = FLT_MAX; bx[s] = 0; }
  int cnt = 0;

  auto drain = [&]() {
    int tt = 0;
    while (__any(tt < cnt)) {
      float d = FLT_MAX;
      int j = 0;
      if (tt < cnt) {
        uint2 e = sbuf[tt][t];
        d = __uint_as_float(e.x);
        j = (int)e.y;
      }
      bool c[KNN];
      #pragma unroll
      for (int s = 0; s < KNN; ++s) c[s] = d < bd[s];
      #pragma unroll
      for (int s = KNN - 1; s >= 1; --s) {
        bd[s] = c[s - 1] ? bd[s - 1] : (c[s] ? d : bd[s]);
        bx[s] = c[s - 1] ? bx[s - 1] : (c[s] ? j : bx[s]);
      }
      bd[0] = c[0] ? d : bd[0];
      bx[0] = c[0] ? j : bx[0];
      ++tt;
    }
    cnt = 0;
  };

  for (int jj = 0; jj < CHUNK; jj += 2) {
    #pragma unroll
    for (int u = 0; u < 2; ++u) {
      float4 p = s4[jj + u];
      float dot = fmaf(zi, p.z, fmaf(yi, p.y, __fmul_rn(xi, p.x)));
      float d = __fadd_rn(__fsub_rn(sqi, __fmul_rn(2.0f, dot)), p.w);
      int j = cbase + jj + u;
      if (j == i) d = __fadd_rn(d, 1e10f);
      if (d < bd[KNN - 1]) {
        sbuf[cnt][t] = make_uint2(__float_as_uint(d), (unsigned)j);
        ++cnt;
      }
    }
    if (__any(cnt >= KNN - 1)) drain();
  }
  drain();

  #pragma unroll
  for (int s = 0; s < KNN; ++s) {
    int slot = blockIdx.y * KNN + s;
    part[(size_t)slot * N_PTS + i] =
        make_uint2(__float_as_uint(bd[s]), (unsigned)bx[s]);
  }
}

// ---------------------------------------------------------------------------
// KNN stage 2 (unchanged R5 16-lane tournament merge).
// ---------------------------------------------------------------------------
__global__ __launch_bounds__(256) void knn_merge_kernel(
    const uint2* __restrict__ part, int* __restrict__ nbr) {
  __shared__ uint2 sl[KNN * 256];     // [slot][tid] : 32 KB
  const int t = threadIdx.x;
  const int c = t & 15;               // chunk this lane owns
  const int i = blockIdx.x * 16 + (t >> 4);

  float hd;  int hj;
  {
    uint2 e0 = part[(size_t)(c * KNN) * N_PTS + i];
    hd = __uint_as_float(e0.x);
    hj = (int)e0.y;
    #pragma unroll
    for (int s = 1; s < KNN; ++s)
      sl[s * 256 + t] = part[(size_t)(c * KNN + s) * N_PTS + i];
  }

  int idx = 1;
  int outj = 0;
  #pragma unroll
  for (int r = 0; r < KNN; ++r) {
    float md = hd;  int mc = c;
    #pragma unroll
    for (int m = 1; m < 16; m <<= 1) {
      float od = __shfl_xor(md, m, 16);
      int oc = __shfl_xor(mc, m, 16);
      bool take = (od < md) || (od == md && oc < mc);
      md = take ? od : md;
      mc = take ? oc : mc;
    }
    int jw = __shfl(hj, mc, 16);
    if (c == r) outj = jw;
    if (c == mc) {
      if (idx < KNN) {
        uint2 e = sl[idx * 256 + t];
        hd = __uint_as_float(e.x);
        hj = (int)e.y;
      } else {
        hd = FLT_MAX;  hj = 0;
      }
      ++idx;
    }
  }
  nbr[i * KNN + c] = outj;
}

// ---------------------------------------------------------------------------
// W1 -> Bt (transposed, n-major) bf16 hi/lo (unchanged).
// ---------------------------------------------------------------------------
__global__ __launch_bounds__(256) void convert_w_kernel(
    const float* __restrict__ W1, short* __restrict__ bhi,
    short* __restrict__ blo) {
  const int n = blockIdx.x;      // 0..511
  const int k = threadIdx.x;     // 0..255
  const float v = (n < 256) ? W1[k * DTOK + n]
                            : W1[(259 + k) * DTOK + (n - 256)];
  short h = f2bf(v);
  bhi[n * 256 + k] = h;
  blo[n * 256 + k] = f2bf(v - bf2f(h));
}

// ---------------------------------------------------------------------------
// pq GEMM v2 (unchanged from R9).
// ---------------------------------------------------------------------------
__global__ __launch_bounds__(256, 2) void pq_gemm_fused_kernel(
    const float* __restrict__ A, const short* __restrict__ Bthi,
    const short* __restrict__ Btlo, const float* __restrict__ xyz,
    const float* __restrict__ W1, const float* __restrict__ b1,
    float* __restrict__ R, float* __restrict__ Q) {
  __shared__ short Ahi[64][32], Alo[64][32];    // 4K + 4K
  __shared__ short Bhi[128][32], Blo[128][32];  // 8K + 8K
  __shared__ float Qs[64][65];                  // 16.6K
  __shared__ float sx[64][3];
  __shared__ float swz[6][64];
  __shared__ float sb1[64];

  const int tid = threadIdx.x;
  const int lane = tid & 63;
  const int wave = tid >> 6;
  const int l15 = lane & 15;
  const int quad = lane >> 4;
  const int mh = wave & 1;
  const int qh = wave >> 1;
  const int m0 = blockIdx.x * 64;
  const int np0 = blockIdx.y * 64;

  if (tid < 64) {
    sx[tid][0] = xyz[(m0 + tid) * 3];
    sx[tid][1] = xyz[(m0 + tid) * 3 + 1];
    sx[tid][2] = xyz[(m0 + tid) * 3 + 2];
  } else if (tid < 128) {
    int n = tid - 64;
    sb1[n] = b1[np0 + n];
    #pragma unroll
    for (int r = 0; r < 3; ++r) {
      swz[r][n] = W1[(256 + r) * DTOK + np0 + n];
      swz[3 + r][n] = W1[(515 + r) * DTOK + np0 + n];
    }
  }

  float4v acc[2][4];
  #pragma unroll
  for (int mf = 0; mf < 2; ++mf)
    #pragma unroll
    for (int nf = 0; nf < 4; ++nf)
      #pragma unroll
      for (int e = 0; e < 4; ++e) acc[mf][nf][e] = 0.f;

  const int ar = tid >> 2;             // A staging row 0..63
  const int ak = (tid & 3) * 8;        // A staging k-offset

  #pragma unroll 1
  for (int kc = 0; kc < 8; ++kc) {
    const int k0 = kc * 32;
    __syncthreads();
    {
      const float* asrc = A + (size_t)(m0 + ar) * 256 + k0 + ak;
      float4 a0 = *(const float4*)asrc;
      float4 a1 = *(const float4*)(asrc + 4);
      float v[8] = {a0.x, a0.y, a0.z, a0.w, a1.x, a1.y, a1.z, a1.w};
      short8 h8, l8;
      #pragma unroll
      for (int e = 0; e < 8; ++e) {
        short h = f2bf(v[e]);
        h8[e] = h;
        l8[e] = f2bf(v[e] - bf2f(h));
      }
      *(short8*)(&Ahi[ar][ak]) = h8;
      *(short8*)(&Alo[ar][ak]) = l8;
    }
    #pragma unroll
    for (int l = 0; l < 4; ++l) {
      const int rem = tid + 256 * (l & 1);
      const int row = rem >> 2;
      const int koff = (rem & 3) * 8;
      const int n = (row < 64) ? (np0 + row) : (256 + np0 + row - 64);
      const short* src = ((l < 2) ? Bthi : Btlo) + (size_t)n * 256 + k0 + koff;
      short8 vv = *(const short8*)src;
      if (l < 2) *(short8*)(&Bhi[row][koff]) = vv;
      else       *(short8*)(&Blo[row][koff]) = vv;
    }
    __syncthreads();

    short8 ah[2], al[2], bh[4], bl[4];
    #pragma unroll
    for (int mf = 0; mf < 2; ++mf) {
      ah[mf] = *(const short8*)(&Ahi[mh * 32 + mf * 16 + l15][quad * 8]);
      al[mf] = *(const short8*)(&Alo[mh * 32 + mf * 16 + l15][quad * 8]);
    }
    #pragma unroll
    for (int nf = 0; nf < 4; ++nf) {
      bh[nf] = *(const short8*)(&Bhi[qh * 64 + nf * 16 + l15][quad * 8]);
      bl[nf] = *(const short8*)(&Blo[qh * 64 + nf * 16 + l15][quad * 8]);
    }
    #pragma unroll
    for (int mf = 0; mf < 2; ++mf)
      #pragma unroll
      for (int nf = 0; nf < 4; ++nf) {
        acc[mf][nf] = __builtin_amdgcn_mfma_f32_16x16x32_bf16(
            ah[mf], bh[nf], acc[mf][nf], 0, 0, 0);
        acc[mf][nf] = __builtin_amdgcn_mfma_f32_16x16x32_bf16(
            ah[mf], bl[nf], acc[mf][nf], 0, 0, 0);
        acc[mf][nf] = __builtin_amdgcn_mfma_f32_16x16x32_bf16(
            al[mf], bh[nf], acc[mf][nf], 0, 0, 0);
      }
  }

  if (qh == 1) {
    #pragma unroll
    for (int mf = 0; mf < 2; ++mf)
      #pragma unroll
      for (int nf = 0; nf < 4; ++nf)
        #pragma unroll
        for (int e = 0; e < 4; ++e) {
          int row = mh * 32 + mf * 16 + quad * 4 + e;
          int col = nf * 16 + l15;
          float q = acc[mf][nf][e] + sx[row][0] * swz[3][col] +
                    sx[row][1] * swz[4][col] + sx[row][2] * swz[5][col];
          Qs[row][col] = q;
          Q[(size_t)(m0 + row) * DTOK + np0 + col] = q;
        }
  }
  __syncthreads();
  if (qh == 0) {
    #pragma unroll
    for (int mf = 0; mf < 2; ++mf)
      #pragma unroll
      for (int nf = 0; nf < 4; ++nf)
        #pragma unroll
        for (int e = 0; e < 4; ++e) {
          int row = mh * 32 + mf * 16 + quad * 4 + e;
          int col = nf * 16 + l15;
          float p = acc[mf][nf][e] + sx[row][0] * swz[0][col] +
                    sx[row][1] * swz[1][col] + sx[row][2] * swz[2][col];
          R[(size_t)(m0 + row) * DTOK + np0 + col] =
              (p + sb1[col]) - Qs[row][col];
        }
  }
}

// ---------------------------------------------------------------------------
// EdgeConv via MFMA. Build loop v3: neighbor indices prefetched ONCE per
// point via a coalesced lane load + __shfl broadcast -- removes the
// nbr-load -> Q-gather serial chain (~900 cyc/iter) that dominated. All 32
// gather addresses are known up-front; full unroll lets the compiler keep
// many dwordx4 gathers in flight. GEMM/epilogue unchanged.
// ---------------------------------------------------------------------------
#define EP 8          // points per group

__global__ __launch_bounds__(256, 2) void edge_mfma_kernel(
    const float* __restrict__ R, const float* __restrict__ Q,
    const int* __restrict__ nbr, const float* __restrict__ W2,
    const float* __restrict__ b2, float* __restrict__ out,
    int num_groups, int groups_per_block) {
  __shared__ short Hs[EP * KNN * DTOK];   // 128 rows x 256, 64 KB
  const int lane = threadIdx.x & 63;
  const int wave = threadIdx.x >> 6;
  const int l15 = lane & 15;
  const int quad = lane >> 4;

  short8 bfr[4][8];
  #pragma unroll
  for (int nt_i = 0; nt_i < 4; ++nt_i) {
    const int n = (wave * 4 + nt_i) * 16 + l15;
    #pragma unroll
    for (int kt = 0; kt < 8; ++kt) {
      short8 f;
      #pragma unroll
      for (int jj = 0; jj < 8; ++jj) {
        int k = kt * 32 + quad * 8 + jj;
        f[jj] = f2bf(W2[k * DTOK + n]);
      }
      bfr[nt_i][kt] = f;
    }
  }

  const int wc8 = lane >> 1;
  const int wsub = (lane & 1) * 4;

  for (int gi = 0; gi < groups_per_block; ++gi) {
    const int g = blockIdx.x + gi * gridDim.x;
    if (g >= num_groups) break;
    const int i0 = g * EP;

    // ---- build H: prefetch nbr + R rows, then pipelined Q gathers ----
    {
      const int ia = i0 + wave * 2;
      const int jr0 = nbr[ia * KNN + l15];
      const int jr1 = nbr[(ia + 1) * KNN + l15];
      const float4 ri0 = ((const float4*)(R + (size_t)ia * DTOK))[lane];
      const float4 ri1 = ((const float4*)(R + (size_t)(ia + 1) * DTOK))[lane];
      #pragma unroll
      for (int pp = 0; pp < 2; ++pp) {
        const float4 ri = pp ? ri1 : ri0;
        const int jr = pp ? jr1 : jr0;
        #pragma unroll
        for (int k = 0; k < KNN; ++k) {
          const int j = __shfl(jr, k, 16);
          const float4 qj = ((const float4*)(Q + (size_t)j * DTOK))[lane];
          const int r = wave * 32 + pp * 16 + k;
          uint2 pk;
          pk.x = ((unsigned)(unsigned short)f2bf(fmaxf(ri.x + qj.x, 0.f))) |
                 (((unsigned)(unsigned short)f2bf(fmaxf(ri.y + qj.y, 0.f))) << 16);
          pk.y = ((unsigned)(unsigned short)f2bf(fmaxf(ri.z + qj.z, 0.f))) |
                 (((unsigned)(unsigned short)f2bf(fmaxf(ri.w + qj.w, 0.f))) << 16);
          *(uint2*)(&Hs[r * DTOK + ((wc8 ^ (r & 7)) << 3) + wsub]) = pk;
        }
      }
    }
    __syncthreads();

    #pragma unroll
    for (int mp = 0; mp < 4; ++mp) {
      float4v acc[2][4];
      #pragma unroll
      for (int mi = 0; mi < 2; ++mi)
        #pragma unroll
        for (int nt_i = 0; nt_i < 4; ++nt_i)
          #pragma unroll
          for (int e = 0; e < 4; ++e) acc[mi][nt_i][e] = 0.f;

      #pragma unroll
      for (int kt = 0; kt < 8; ++kt) {
        const int pc = ((kt * 4 + quad) ^ (l15 & 7)) << 3;
        const short8 a0 = *(const short8*)(
            &Hs[((mp * 2 + 0) * 16 + l15) * DTOK + pc]);
        const short8 a1 = *(const short8*)(
            &Hs[((mp * 2 + 1) * 16 + l15) * DTOK + pc]);
        #pragma unroll
        for (int nt_i = 0; nt_i < 4; ++nt_i) {
          acc[0][nt_i] = __builtin_amdgcn_mfma_f32_16x16x32_bf16(
              a0, bfr[nt_i][kt], acc[0][nt_i], 0, 0, 0);
          acc[1][nt_i] = __builtin_amdgcn_mfma_f32_16x16x32_bf16(
              a1, bfr[nt_i][kt], acc[1][nt_i], 0, 0, 0);
        }
      }

      #pragma unroll
      for (int mi = 0; mi < 2; ++mi) {
        #pragma unroll
        for (int nt_i = 0; nt_i < 4; ++nt_i) {
          float rm = fmaxf(fmaxf(acc[mi][nt_i][0], acc[mi][nt_i][1]),
                           fmaxf(acc[mi][nt_i][2], acc[mi][nt_i][3]));
          rm = fmaxf(rm, __shfl_xor(rm, 16, 64));
          rm = fmaxf(rm, __shfl_xor(rm, 32, 64));
          if (lane < 16) {
            const int i = i0 + mp * 2 + mi;
            const int n = (wave * 4 + nt_i) * 16 + lane;
            out[(size_t)i * DTOK + n] = rm + b2[n];
          }
        }
      }
    }
    __syncthreads();
  }
}

// ---------------------------------------------------------------------------
extern "C" void kernel_launch(void* const* d_in, const int* in_sizes, int n_in,
                              void* d_out, int out_size, void* d_ws,
                              size_t ws_size, hipStream_t stream) {
  const float* xyz = (const float*)d_in[0];
  const float* feat = (const float*)d_in[1];
  const float* W1a = (const float*)d_in[2];
  const float* b1a = (const float*)d_in[3];
  const float* W2a = (const float*)d_in[4];
  const float* b2a = (const float*)d_in[5];
  const float* W1b = (const float*)d_in[6];
  const float* b1b = (const float*)d_in[7];
  const float* W2b = (const float*)d_in[8];
  const float* b2b = (const float*)d_in[9];
  float* out = (float*)d_out;

  // ws layout (25 MB): nbr 0.5 | 16MB (knn: part / gemm: R at +8MB)
  //                    | Q 8MB | Bt hi/lo 0.5MB.  Layer-a staging in d_out.
  char* w = (char*)d_ws;
  const size_t SZ_NBR = (size_t)N_PTS * KNN * sizeof(int);        // 512 KB
  const size_t MB = 1024 * 1024;
  int* nbr = (int*)w;
  char* w1 = w + SZ_NBR;
  uint2* part = (uint2*)w1;                    // knn phase (16 MB)
  float* R = (float*)(w1 + 8 * MB);            // 8 MB (post-knn)
  float* Q = (float*)(w + SZ_NBR + 16 * MB);   // 8 MB
  short* Bthi = (short*)(w + SZ_NBR + 24 * MB);// 256 KB
  short* Btlo = Bthi + 512 * 256;              // 256 KB
  float* bufC = out;                           // layer-a output staging

  knn_partial_kernel<<<dim3(N_PTS / 256, NCHUNK), 256, 0, stream>>>(xyz, part);
  knn_merge_kernel<<<N_PTS / 16, 256, 0, stream>>>(part, nbr);

  const int num_groups = N_PTS / EP;           // 1024
  const int nblocks = 512;

  // layer a
  convert_w_kernel<<<512, 256, 0, stream>>>(W1a, Bthi, Btlo);
  pq_gemm_fused_kernel<<<dim3(N_PTS / 64, 4), 256, 0, stream>>>(
      feat, Bthi, Btlo, xyz, W1a, b1a, R, Q);
  edge_mfma_kernel<<<nblocks, 256, 0, stream>>>(R, Q, nbr, W2a, b2a, bufC,
                                                num_groups, 2);

  // layer b
  convert_w_kernel<<<512, 256, 0, stream>>>(W1b, Bthi, Btlo);
  pq_gemm_fused_kernel<<<dim3(N_PTS / 64, 4), 256, 0, stream>>>(
      bufC, Bthi, Btlo, xyz, W1b, b1b, R, Q);
  edge_mfma_kernel<<<nblocks, 256, 0, stream>>>(R, Q, nbr, W2b, b2b, out,
                                                num_groups, 2);
}